// Round 17
// baseline (177.726 us; speedup 1.0000x reference)
//
#include <hip/hip_runtime.h>

#define NB 8
#define NN 10000
#define NE 160000
#define NNODES (NB*NN)          // 80000
#define NEDGE (NB*NE)           // 1280000
#define FIN 5
#define HID 128
#define EMB 256
#define ALAST 10
#define PROJ_IN (HID*5 + ALAST + 1)  // 651
#define NPOS 40                      // 5 positions x 8 batches
#define E0CAP 256                    // in-edges kept per position node
#define TCAP (NPOS + NPOS*E0CAP)     // 10280 max T slots (realistically ~720)
#define E1C 128                      // in-edges kept per T slot (Poisson(16))
#define NBLK ((NNODES+255)/256)      // 313

// markT encoding: -1 none, >=0 T slot, -2 transient CAS claim, -3 degree-needed-only
// cnts: [0]=nT; per-position e0 counters at stride-16 ints (64B padded).
#define C_NT 0
#define C_E0(t) (8 + (t)*16)

// clear all control state in one dispatch (replaces two memsets)
__global__ void k_clear(int* __restrict__ markT, int* __restrict__ degCnt,
                        int* __restrict__ cnts, int* __restrict__ e1cnt) {
    int i = blockIdx.x*256 + threadIdx.x;
    if (i < NNODES) { markT[i] = -1; degCnt[i] = 0; }
    if (i < 1024) cnts[i] = 0;
    for (int j = i; j < TCAP*4; j += NNODES) e1cnt[j] = 0;
}

// Mark the 40 position nodes; in-wave ballot dedupe.
__global__ void k_mark(const int* __restrict__ avail, const int* __restrict__ pos,
                       int* __restrict__ markT, int* __restrict__ Tnodes,
                       int* __restrict__ cnts,
                       int* __restrict__ pos2t0, int* __restrict__ posNode) {
    int p = threadIdx.x;                    // 0..63, active p<40
    int n = 0;
    if (p < NPOS) {
        int b = p / 5, pi = p - b*5;
        int node = (pi < 4) ? avail[b*4 + pi] : pos[b];
        n = node + b*NN;
    }
    int firstIdx = p;
    for (int q = 0; q < NPOS; ++q) {
        int nq = __shfl(n, q, 64);
        if (p < NPOS && q < p && nq == n && firstIdx == p) firstIdx = q;
    }
    bool isFirst = (p < NPOS) && (firstIdx == p);
    unsigned long long bal = __ballot(isFirst);
    if (p < NPOS) {
        int slot = __popcll(bal & ((1ull << firstIdx) - 1ull));
        if (isFirst) {
            markT[n] = slot; Tnodes[slot] = n;
        }
        pos2t0[p] = slot; posNode[p] = n;
    }
    if (p == 0) cnts[C_NT] = __popcll(bal);
}

// pass1: edges into T0 -> e0 lists (40 padded counters, low contention)
__global__ __launch_bounds__(256) void k_pass1(const int* __restrict__ edges,
        const int* __restrict__ markT, int* __restrict__ cnts,
        int* __restrict__ e0) {
    int idx = blockIdx.x*256 + threadIdx.x;         // 0..NEDGE/4-1
    int g = idx / (NE/4), w4 = idx - g*(NE/4);
    const int* base = edges + (size_t)g*2*NE;
    int4 d4 = ((const int4*)(base + NE))[w4];
    int gofs = g*NN;
    int dd[4] = {d4.x, d4.y, d4.z, d4.w};
    #pragma unroll
    for (int c = 0; c < 4; ++c) {
        int t0 = markT[gofs + dd[c]];
        if (t0 >= 0) {
            int s = base[4*w4 + c] + gofs;
            int k = atomicAdd(&cnts[C_E0(t0)], 1);
            if (k < E0CAP) e0[t0*E0CAP + k] = s;
        }
    }
}

// dedup, parallel: 40 blocks (one per e0 list), one item per thread.
__global__ __launch_bounds__(256) void k_dedup(const int* __restrict__ e0,
                        int* __restrict__ cnts, int* __restrict__ markT,
                        int* __restrict__ Tnodes) {
    __shared__ int lc, base;
    int t0 = blockIdx.x;
    if (threadIdx.x == 0) lc = 0;
    __syncthreads();
    int m = cnts[C_E0(t0)]; if (m > E0CAP) m = E0CAP;
    int s = -1, myIdx = -1;
    if ((int)threadIdx.x < m) {
        s = e0[t0*E0CAP + threadIdx.x];
        if (atomicCAS(&markT[s], -1, -2) == -1)
            myIdx = atomicAdd(&lc, 1);              // LDS atomic
    }
    __syncthreads();
    if (threadIdx.x == 0 && lc > 0) base = atomicAdd(&cnts[C_NT], lc);
    __syncthreads();
    if (myIdx >= 0) {
        int slot = base + myIdx;                    // < TCAP by construction
        Tnodes[slot] = s;
        markT[s] = slot;
    }
}

// pass2: edges into T -> per-slot e1 lists; T-node degree counted here
// (the ts>=0 branch fires once per edge into T, which IS deg of T nodes);
// sources marked degree-needed (-3) with plain stores.
__global__ __launch_bounds__(256) void k_pass2(const int* __restrict__ edges,
        int* __restrict__ markT, int* __restrict__ e1cnt, int* __restrict__ e1,
        int* __restrict__ degCnt) {
    int idx = blockIdx.x*256 + threadIdx.x;
    int g = idx / (NE/4), w4 = idx - g*(NE/4);
    const int* base = edges + (size_t)g*2*NE;
    int4 d4 = ((const int4*)(base + NE))[w4];
    int gofs = g*NN;
    int dd[4] = {d4.x, d4.y, d4.z, d4.w};
    #pragma unroll
    for (int c = 0; c < 4; ++c) {
        int d = gofs + dd[c];
        int ts = markT[d];
        if (ts >= 0) {
            int s = base[4*w4 + c] + gofs;
            int k = atomicAdd(&e1cnt[ts*4], 1);     // 16B-padded counter
            if (k < E1C) e1[(size_t)ts*E1C + k] = s;
            atomicAdd(&degCnt[d], 1);               // T-node degree
            if (markT[s] == -1) markT[s] = -3;      // benign same-value race
        }
    }
}

// pass3: degree count for degree-needed-only sources (-3)
__global__ __launch_bounds__(256) void k_pass3(const int* __restrict__ edges,
        const int* __restrict__ markT, int* __restrict__ degCnt) {
    int idx = blockIdx.x*256 + threadIdx.x;
    int g = idx / (NE/4), w4 = idx - g*(NE/4);
    int4 d4 = ((const int4*)(edges + (size_t)g*2*NE + NE))[w4];
    int gofs = g*NN;
    int dd[4] = {d4.x, d4.y, d4.z, d4.w};
    #pragma unroll
    for (int c = 0; c < 4; ++c) {
        int n = gofs + dd[c];
        if (markT[n] == -3) atomicAdd(&degCnt[n], 1);
    }
}

// Fused layer-1 agg + layer-1 dense + layer-2 dense over T slots.
#define KC 32
__global__ __launch_bounds__(256) void k_h12T(
        const int* __restrict__ e1cnt, const int* __restrict__ e1,
        const int* __restrict__ Tnodes,
        const int* __restrict__ degCnt, const int* __restrict__ cnts,
        const float* __restrict__ xg,
        const float* __restrict__ W1, const float* __restrict__ b1,
        const float* __restrict__ W2, float* __restrict__ hsT) {
    __shared__ float axs[FIN][128];
    __shared__ float w1s[FIN][128];
    __shared__ float b1s[128];
    __shared__ float dvs[128];
    __shared__ float xs[KC*128];
    __shared__ float wt[KC*64];
    int ntv = cnts[C_NT]; if (ntv > TCAP) ntv = TCAP;
    int jb  = blockIdx.x & 1;
    int m0g = (blockIdx.x >> 1) * 128;
    if (m0g >= ntv) return;
    int tid = threadIdx.x;
    if (tid < 128) {
        b1s[tid] = b1[tid];
        #pragma unroll
        for (int f = 0; f < FIN; ++f) w1s[f][tid] = W1[tid*FIN + f];
    } else {
        int r2 = tid - 128;
        int row = m0g + r2;
        int ok = row < ntv;
        int node = ok ? Tnodes[row] : 0;
        float dvv = ok ? rsqrtf(1.0f + (float)degCnt[node]) : 0.0f;
        dvs[r2] = dvv;
        float acc[FIN];
        #pragma unroll
        for (int f = 0; f < FIN; ++f) acc[f] = xg[(size_t)node*FIN + f]*dvv;
        if (ok) {
            int m = e1cnt[row*4]; if (m > E1C) m = E1C;
            const int* lp = e1 + (size_t)row*E1C;
            for (int j = 0; j < m; ++j) {
                int s = lp[j];
                float dv = rsqrtf(1.0f + (float)degCnt[s]);
                const float* xr = xg + (size_t)s*FIN;
                #pragma unroll
                for (int f = 0; f < FIN; ++f) acc[f] += xr[f]*dv;
            }
        }
        #pragma unroll
        for (int f = 0; f < FIN; ++f) axs[f][r2] = acc[f];
    }
    int tx = tid & 15, ty = tid >> 4;
    int m0 = ty*8;
    int j0 = tx*4;
    int r  = tid >> 1;
    int kq = (tid & 1) * 16;
    int rw  = tid >> 2;
    int kqw = (tid & 3) * 8;
    float a[8][4];
    #pragma unroll
    for (int i = 0; i < 8; ++i)
        #pragma unroll
        for (int j = 0; j < 4; ++j) a[i][j] = 0.f;
    __syncthreads();
    float axr[FIN];
    float dvr = dvs[r];
    #pragma unroll
    for (int f = 0; f < FIN; ++f) axr[f] = axs[f][r] * dvr;

    for (int kh = 0; kh < 128; kh += KC) {
        float4 wv0 = *(const float4*)&W2[(size_t)(jb*64 + rw)*128 + kh + kqw];
        float4 wv1 = *(const float4*)&W2[(size_t)(jb*64 + rw)*128 + kh + kqw + 4];
        float hv[16];
        #pragma unroll
        for (int kk = 0; kk < 16; ++kk) {
            int k1 = kh + kq + kk;
            float sv = b1s[k1];
            #pragma unroll
            for (int f = 0; f < FIN; ++f) sv += axr[f]*w1s[f][k1];
            hv[kk] = fmaxf(sv, 0.0f);
        }
        __syncthreads();
        #pragma unroll
        for (int kk = 0; kk < 16; ++kk) xs[(kq+kk)*128 + r] = hv[kk];
        wt[(kqw+0)*64 + rw] = wv0.x;
        wt[(kqw+1)*64 + rw] = wv0.y;
        wt[(kqw+2)*64 + rw] = wv0.z;
        wt[(kqw+3)*64 + rw] = wv0.w;
        wt[(kqw+4)*64 + rw] = wv1.x;
        wt[(kqw+5)*64 + rw] = wv1.y;
        wt[(kqw+6)*64 + rw] = wv1.z;
        wt[(kqw+7)*64 + rw] = wv1.w;
        __syncthreads();
        for (int k = 0; k < KC; ++k) {
            float4 xa = *(const float4*)&xs[k*128 + m0];
            float4 xb = *(const float4*)&xs[k*128 + m0 + 4];
            float4 wa = *(const float4*)&wt[k*64 + j0];
            float xr[8] = {xa.x,xa.y,xa.z,xa.w,xb.x,xb.y,xb.z,xb.w};
            #pragma unroll
            for (int i = 0; i < 8; ++i) {
                a[i][0] += xr[i]*wa.x;
                a[i][1] += xr[i]*wa.y;
                a[i][2] += xr[i]*wa.z;
                a[i][3] += xr[i]*wa.w;
            }
        }
    }
    #pragma unroll
    for (int i = 0; i < 8; ++i) {
        int row = m0g + m0 + i;
        if (row < ntv) {
            float dv = dvs[m0 + i];
            float4 v0 = make_float4(a[i][0]*dv, a[i][1]*dv, a[i][2]*dv, a[i][3]*dv);
            *(float4*)&hsT[(size_t)row*HID + jb*64 + j0] = v0;
        }
    }
}

// MLP1 with fused layer-2 aggregation: block per (batch, 16-output group).
// Stage slot lists for the batch's 5 positions once (LDS), aggregate hsT rows
// into c[], then the 16-lane shuffle-reduce dot as before.
__global__ __launch_bounds__(256) void k_mlp1(
        const int* __restrict__ pos2t0, const int* __restrict__ posNode,
        const int* __restrict__ e1cnt, const int* __restrict__ e1,
        const int* __restrict__ markT, const float* __restrict__ hsT,
        const int* __restrict__ degCnt, const float* __restrict__ b2,
        const float* __restrict__ actions, const float* __restrict__ steps,
        const float* __restrict__ Wp1, const float* __restrict__ bp1,
        float* __restrict__ hm) {
    int b  = blockIdx.x >> 4;
    int jg = blockIdx.x & 15;
    int t  = threadIdx.x;
    __shared__ float c[PROJ_IN];
    __shared__ int slots[5*E1C];
    __shared__ int cm[5], t0s[5];
    __shared__ float dvP[5];
    // stage per-position slot lists
    if (t < 5) {
        int t0 = pos2t0[b*5 + t];
        t0s[t] = t0;
        int m = e1cnt[t0*4]; if (m > E1C) m = E1C;
        cm[t] = m;
        dvP[t] = rsqrtf(1.0f + (float)degCnt[posNode[b*5 + t]]);
    }
    __syncthreads();
    for (int i = t; i < 5*E1C; i += 256) {
        int p5 = i >> 7, j = i & (E1C-1);
        if (j < cm[p5]) slots[i] = markT[e1[(size_t)t0s[p5]*E1C + j]];
    }
    __syncthreads();
    // aggregate: c[p5*128+f] = relu(dv*(hsT[t0]+sum hsT[slot]) + b2[f])
    for (int i = t; i < 5*HID; i += 256) {
        int p5 = i >> 7, f = i & 127;
        float acc = hsT[(size_t)t0s[p5]*HID + f];
        int m = cm[p5];
        const int* sp = &slots[p5*E1C];
        for (int j = 0; j < m; ++j) {
            int ts = sp[j];
            if (ts >= 0) acc += hsT[(size_t)ts*HID + f];
        }
        c[i] = fmaxf(acc*dvP[p5] + b2[f], 0.0f);
    }
    if (t < ALAST) c[5*HID + t] = actions[b*ALAST + t];
    if (t == ALAST) c[5*HID + ALAST] = steps[b];
    __syncthreads();
    int o = t >> 4, sub = t & 15;
    int j = jg*16 + o;
    const float* wr = Wp1 + (size_t)j*PROJ_IN;
    float s = 0.f;
    for (int k = sub; k < PROJ_IN; k += 16) s += c[k]*wr[k];
    #pragma unroll
    for (int d = 8; d; d >>= 1) s += __shfl_down(s, d, 16);
    if (sub == 0) hm[b*EMB + j] = fmaxf(s + bp1[j], 0.f);
}

// MLP2
__global__ __launch_bounds__(256) void k_mlp2(
        const float* __restrict__ hm, const float* __restrict__ Wp2,
        const float* __restrict__ bp2, float* __restrict__ out) {
    int b  = blockIdx.x >> 4;
    int jg = blockIdx.x & 15;
    int t  = threadIdx.x;
    __shared__ float c[EMB];
    if (t < EMB) c[t] = hm[b*EMB + t];
    __syncthreads();
    int o = t >> 4, sub = t & 15;
    int j = jg*16 + o;
    const float* wr = Wp2 + (size_t)j*EMB;
    float s = 0.f;
    for (int k = sub; k < EMB; k += 16) s += c[k]*wr[k];
    #pragma unroll
    for (int d = 8; d; d >>= 1) s += __shfl_down(s, d, 16);
    if (sub == 0) out[b*EMB + j] = s + bp2[j];
}

extern "C" void kernel_launch(void* const* d_in, const int* in_sizes, int n_in,
                              void* d_out, int out_size, void* d_ws, size_t ws_size,
                              hipStream_t stream) {
    const float* graph_x = (const float*)d_in[0];
    const int*   edges   = (const int*)d_in[1];
    const int*   pos     = (const int*)d_in[2];
    const int*   avail   = (const int*)d_in[3];
    const float* actions = (const float*)d_in[4];
    const float* steps   = (const float*)d_in[5];
    const float* W1  = (const float*)d_in[6];
    const float* b1  = (const float*)d_in[7];
    const float* W2  = (const float*)d_in[8];
    const float* b2  = (const float*)d_in[9];
    const float* Wp1 = (const float*)d_in[10];
    const float* bp1 = (const float*)d_in[11];
    const float* Wp2 = (const float*)d_in[12];
    const float* bp2 = (const float*)d_in[13];
    float* out = (float*)d_out;

    char* ws = (char*)d_ws;
    size_t off = 0;
    #define ALLOC(ptrname, type, nelem) \
        type* ptrname = (type*)(ws + off); off = (off + (size_t)(nelem)*sizeof(type) + 255) & ~(size_t)255;
    ALLOC(markT,   int,   NNODES)
    ALLOC(degCnt,  int,   NNODES)
    ALLOC(cnts,    int,   1024)
    ALLOC(e1cnt,   int,   TCAP*4)
    ALLOC(Tnodes,  int,   TCAP)
    ALLOC(pos2t0,  int,   NPOS)
    ALLOC(posNode, int,   NPOS)
    ALLOC(e0,      int,   NPOS*E0CAP)
    ALLOC(e1,      int,   (size_t)TCAP*E1C)
    ALLOC(hsT,     float, (size_t)TCAP*HID)
    ALLOC(hm,      float, (size_t)NB*EMB)
    #undef ALLOC

    k_clear<<<NBLK, 256, 0, stream>>>(markT, degCnt, cnts, e1cnt);
    k_mark<<<1, 64, 0, stream>>>(avail, pos, markT, Tnodes, cnts, pos2t0, posNode);
    k_pass1<<<NEDGE/4/256, 256, 0, stream>>>(edges, markT, cnts, e0);
    k_dedup<<<NPOS, 256, 0, stream>>>(e0, cnts, markT, Tnodes);
    k_pass2<<<NEDGE/4/256, 256, 0, stream>>>(edges, markT, e1cnt, e1, degCnt);
    k_pass3<<<NEDGE/4/256, 256, 0, stream>>>(edges, markT, degCnt);
    k_h12T<<<2*((TCAP+127)/128), 256, 0, stream>>>(e1cnt, e1, Tnodes, degCnt, cnts,
                                                   graph_x, W1, b1, W2, hsT);
    k_mlp1<<<NB*16, 256, 0, stream>>>(pos2t0, posNode, e1cnt, e1, markT, hsT,
                                      degCnt, b2, actions, steps, Wp1, bp1, hm);
    k_mlp2<<<NB*16, 256, 0, stream>>>(hm, Wp2, bp2, out);
}

// Round 18
// 165.259 us; speedup vs baseline: 1.0754x; 1.0754x over previous
//
#include <hip/hip_runtime.h>

#define NB 8
#define NN 10000
#define NE 160000
#define NNODES (NB*NN)          // 80000
#define NEDGE (NB*NE)           // 1280000
#define FIN 5
#define HID 128
#define EMB 256
#define ALAST 10
#define PROJ_IN (HID*5 + ALAST + 1)  // 651
#define NPOS 40                      // 5 positions x 8 batches
#define E0CAP 256                    // in-edges kept per position node
#define TCAP (NPOS + NPOS*E0CAP)     // 10280 max T slots (realistically ~720)
#define E1C 128                      // in-edges kept per T slot (Poisson(16))
#define NBLK ((NNODES+255)/256)      // 313

// markT encoding: -1 none, >=0 T slot, -2 transient CAS claim, -3 degree-needed-only
// cnts: [0]=nT; per-position e0 counters at stride-16 ints (64B padded).
#define C_NT 0
#define C_E0(t) (8 + (t)*16)

// clear all control state in one dispatch
__global__ void k_clear(int* __restrict__ markT, int* __restrict__ degCnt,
                        int* __restrict__ cnts, int* __restrict__ e1cnt) {
    int i = blockIdx.x*256 + threadIdx.x;
    if (i < NNODES) { markT[i] = -1; degCnt[i] = 0; }
    if (i < 1024) cnts[i] = 0;
    for (int j = i; j < TCAP*4; j += NNODES) e1cnt[j] = 0;
}

// Mark the 40 position nodes; in-wave ballot dedupe.
__global__ void k_mark(const int* __restrict__ avail, const int* __restrict__ pos,
                       int* __restrict__ markT, int* __restrict__ Tnodes,
                       int* __restrict__ cnts,
                       int* __restrict__ pos2t0, int* __restrict__ posNode) {
    int p = threadIdx.x;                    // 0..63, active p<40
    int n = 0;
    if (p < NPOS) {
        int b = p / 5, pi = p - b*5;
        int node = (pi < 4) ? avail[b*4 + pi] : pos[b];
        n = node + b*NN;
    }
    int firstIdx = p;
    for (int q = 0; q < NPOS; ++q) {
        int nq = __shfl(n, q, 64);
        if (p < NPOS && q < p && nq == n && firstIdx == p) firstIdx = q;
    }
    bool isFirst = (p < NPOS) && (firstIdx == p);
    unsigned long long bal = __ballot(isFirst);
    if (p < NPOS) {
        int slot = __popcll(bal & ((1ull << firstIdx) - 1ull));
        if (isFirst) {
            markT[n] = slot; Tnodes[slot] = n;
        }
        pos2t0[p] = slot; posNode[p] = n;
    }
    if (p == 0) cnts[C_NT] = __popcll(bal);
}

// pass1: edges into T0 -> e0 lists (40 padded counters, low contention)
__global__ __launch_bounds__(256) void k_pass1(const int* __restrict__ edges,
        const int* __restrict__ markT, int* __restrict__ cnts,
        int* __restrict__ e0) {
    int idx = blockIdx.x*256 + threadIdx.x;         // 0..NEDGE/4-1
    int g = idx / (NE/4), w4 = idx - g*(NE/4);
    const int* base = edges + (size_t)g*2*NE;
    int4 d4 = ((const int4*)(base + NE))[w4];
    int gofs = g*NN;
    int dd[4] = {d4.x, d4.y, d4.z, d4.w};
    #pragma unroll
    for (int c = 0; c < 4; ++c) {
        int t0 = markT[gofs + dd[c]];
        if (t0 >= 0) {
            int s = base[4*w4 + c] + gofs;
            int k = atomicAdd(&cnts[C_E0(t0)], 1);
            if (k < E0CAP) e0[t0*E0CAP + k] = s;
        }
    }
}

// dedup, parallel: 40 blocks (one per e0 list), one item per thread.
__global__ __launch_bounds__(256) void k_dedup(const int* __restrict__ e0,
                        int* __restrict__ cnts, int* __restrict__ markT,
                        int* __restrict__ Tnodes) {
    __shared__ int lc, base;
    int t0 = blockIdx.x;
    if (threadIdx.x == 0) lc = 0;
    __syncthreads();
    int m = cnts[C_E0(t0)]; if (m > E0CAP) m = E0CAP;
    int s = -1, myIdx = -1;
    if ((int)threadIdx.x < m) {
        s = e0[t0*E0CAP + threadIdx.x];
        if (atomicCAS(&markT[s], -1, -2) == -1)
            myIdx = atomicAdd(&lc, 1);              // LDS atomic
    }
    __syncthreads();
    if (threadIdx.x == 0 && lc > 0) base = atomicAdd(&cnts[C_NT], lc);
    __syncthreads();
    if (myIdx >= 0) {
        int slot = base + myIdx;                    // < TCAP by construction
        Tnodes[slot] = s;
        markT[s] = slot;
    }
}

// pass2: edges into T -> per-slot e1 lists; T-node degree counted here;
// sources marked degree-needed (-3) with plain stores.
__global__ __launch_bounds__(256) void k_pass2(const int* __restrict__ edges,
        int* __restrict__ markT, int* __restrict__ e1cnt, int* __restrict__ e1,
        int* __restrict__ degCnt) {
    int idx = blockIdx.x*256 + threadIdx.x;
    int g = idx / (NE/4), w4 = idx - g*(NE/4);
    const int* base = edges + (size_t)g*2*NE;
    int4 d4 = ((const int4*)(base + NE))[w4];
    int gofs = g*NN;
    int dd[4] = {d4.x, d4.y, d4.z, d4.w};
    #pragma unroll
    for (int c = 0; c < 4; ++c) {
        int d = gofs + dd[c];
        int ts = markT[d];
        if (ts >= 0) {
            int s = base[4*w4 + c] + gofs;
            int k = atomicAdd(&e1cnt[ts*4], 1);     // 16B-padded counter
            if (k < E1C) e1[(size_t)ts*E1C + k] = s;
            atomicAdd(&degCnt[d], 1);               // T-node degree
            if (markT[s] == -1) markT[s] = -3;      // benign same-value race
        }
    }
}

// pass3: degree count for degree-needed-only sources (-3)
__global__ __launch_bounds__(256) void k_pass3(const int* __restrict__ edges,
        const int* __restrict__ markT, int* __restrict__ degCnt) {
    int idx = blockIdx.x*256 + threadIdx.x;
    int g = idx / (NE/4), w4 = idx - g*(NE/4);
    int4 d4 = ((const int4*)(edges + (size_t)g*2*NE + NE))[w4];
    int gofs = g*NN;
    int dd[4] = {d4.x, d4.y, d4.z, d4.w};
    #pragma unroll
    for (int c = 0; c < 4; ++c) {
        int n = gofs + dd[c];
        if (markT[n] == -3) atomicAdd(&degCnt[n], 1);
    }
}

// aggT: layer-1 aggregation, one WAVE per T slot; lanes cover the e1 list in
// parallel, 5-element shuffle-reduce, lane 0 plain-stores axT (no atomics).
__global__ __launch_bounds__(256) void k_aggT(
        const int* __restrict__ e1cnt, const int* __restrict__ e1,
        const int* __restrict__ degCnt, const int* __restrict__ cnts,
        const float* __restrict__ xg, float* __restrict__ axT) {
    int slot = blockIdx.x*4 + (threadIdx.x >> 6);
    int lane = threadIdx.x & 63;
    int ntv = cnts[C_NT]; if (ntv > TCAP) ntv = TCAP;
    if (slot >= ntv) return;
    int m = e1cnt[slot*4]; if (m > E1C) m = E1C;
    float acc[FIN] = {0.f, 0.f, 0.f, 0.f, 0.f};
    for (int j = lane; j < m; j += 64) {
        int s = e1[(size_t)slot*E1C + j];
        float dv = rsqrtf(1.0f + (float)degCnt[s]);
        const float* xr = xg + (size_t)s*FIN;
        #pragma unroll
        for (int f = 0; f < FIN; ++f) acc[f] += xr[f]*dv;
    }
    #pragma unroll
    for (int f = 0; f < FIN; ++f) {
        #pragma unroll
        for (int d = 32; d; d >>= 1) acc[f] += __shfl_down(acc[f], d, 64);
    }
    if (lane == 0) {
        #pragma unroll
        for (int f = 0; f < FIN; ++f) axT[(size_t)slot*FIN + f] = acc[f];
    }
}

// Fused layer-1 dense + layer-2 dense over T slots; A-tile = axT + self term.
#define KC 32
__global__ __launch_bounds__(256) void k_h12T(
        const float* __restrict__ axT, const int* __restrict__ Tnodes,
        const int* __restrict__ degCnt, const int* __restrict__ cnts,
        const float* __restrict__ xg,
        const float* __restrict__ W1, const float* __restrict__ b1,
        const float* __restrict__ W2, float* __restrict__ hsT) {
    __shared__ float axs[FIN][128];
    __shared__ float w1s[FIN][128];
    __shared__ float b1s[128];
    __shared__ float dvs[128];
    __shared__ float xs[KC*128];
    __shared__ float wt[KC*64];
    int ntv = cnts[C_NT]; if (ntv > TCAP) ntv = TCAP;
    int jb  = blockIdx.x & 1;
    int m0g = (blockIdx.x >> 1) * 128;
    if (m0g >= ntv) return;
    int tid = threadIdx.x;
    if (tid < 128) {
        b1s[tid] = b1[tid];
        #pragma unroll
        for (int f = 0; f < FIN; ++f) w1s[f][tid] = W1[tid*FIN + f];
    } else {
        int r2 = tid - 128;
        int row = m0g + r2;
        int ok = row < ntv;
        int node = ok ? Tnodes[row] : 0;
        float dvv = ok ? rsqrtf(1.0f + (float)degCnt[node]) : 0.0f;
        dvs[r2] = dvv;
        #pragma unroll
        for (int f = 0; f < FIN; ++f)
            axs[f][r2] = ok ? (axT[(size_t)row*FIN + f]
                               + xg[(size_t)node*FIN + f]*dvv) : 0.0f;
    }
    int tx = tid & 15, ty = tid >> 4;
    int m0 = ty*8;
    int j0 = tx*4;
    int r  = tid >> 1;
    int kq = (tid & 1) * 16;
    int rw  = tid >> 2;
    int kqw = (tid & 3) * 8;
    float a[8][4];
    #pragma unroll
    for (int i = 0; i < 8; ++i)
        #pragma unroll
        for (int j = 0; j < 4; ++j) a[i][j] = 0.f;
    __syncthreads();
    float axr[FIN];
    float dvr = dvs[r];
    #pragma unroll
    for (int f = 0; f < FIN; ++f) axr[f] = axs[f][r] * dvr;

    for (int kh = 0; kh < 128; kh += KC) {
        float4 wv0 = *(const float4*)&W2[(size_t)(jb*64 + rw)*128 + kh + kqw];
        float4 wv1 = *(const float4*)&W2[(size_t)(jb*64 + rw)*128 + kh + kqw + 4];
        float hv[16];
        #pragma unroll
        for (int kk = 0; kk < 16; ++kk) {
            int k1 = kh + kq + kk;
            float sv = b1s[k1];
            #pragma unroll
            for (int f = 0; f < FIN; ++f) sv += axr[f]*w1s[f][k1];
            hv[kk] = fmaxf(sv, 0.0f);
        }
        __syncthreads();
        #pragma unroll
        for (int kk = 0; kk < 16; ++kk) xs[(kq+kk)*128 + r] = hv[kk];
        wt[(kqw+0)*64 + rw] = wv0.x;
        wt[(kqw+1)*64 + rw] = wv0.y;
        wt[(kqw+2)*64 + rw] = wv0.z;
        wt[(kqw+3)*64 + rw] = wv0.w;
        wt[(kqw+4)*64 + rw] = wv1.x;
        wt[(kqw+5)*64 + rw] = wv1.y;
        wt[(kqw+6)*64 + rw] = wv1.z;
        wt[(kqw+7)*64 + rw] = wv1.w;
        __syncthreads();
        for (int k = 0; k < KC; ++k) {
            float4 xa = *(const float4*)&xs[k*128 + m0];
            float4 xb = *(const float4*)&xs[k*128 + m0 + 4];
            float4 wa = *(const float4*)&wt[k*64 + j0];
            float xr[8] = {xa.x,xa.y,xa.z,xa.w,xb.x,xb.y,xb.z,xb.w};
            #pragma unroll
            for (int i = 0; i < 8; ++i) {
                a[i][0] += xr[i]*wa.x;
                a[i][1] += xr[i]*wa.y;
                a[i][2] += xr[i]*wa.z;
                a[i][3] += xr[i]*wa.w;
            }
        }
    }
    #pragma unroll
    for (int i = 0; i < 8; ++i) {
        int row = m0g + m0 + i;
        if (row < ntv) {
            float dv = dvs[m0 + i];
            float4 v0 = make_float4(a[i][0]*dv, a[i][1]*dv, a[i][2]*dv, a[i][3]*dv);
            *(float4*)&hsT[(size_t)row*HID + jb*64 + j0] = v0;
        }
    }
}

// MLP1 with fused layer-2 aggregation: block per (batch, 16-output group).
__global__ __launch_bounds__(256) void k_mlp1(
        const int* __restrict__ pos2t0, const int* __restrict__ posNode,
        const int* __restrict__ e1cnt, const int* __restrict__ e1,
        const int* __restrict__ markT, const float* __restrict__ hsT,
        const int* __restrict__ degCnt, const float* __restrict__ b2,
        const float* __restrict__ actions, const float* __restrict__ steps,
        const float* __restrict__ Wp1, const float* __restrict__ bp1,
        float* __restrict__ hm) {
    int b  = blockIdx.x >> 4;
    int jg = blockIdx.x & 15;
    int t  = threadIdx.x;
    __shared__ float c[PROJ_IN];
    __shared__ int slots[5*E1C];
    __shared__ int cm[5], t0s[5];
    __shared__ float dvP[5];
    if (t < 5) {
        int t0 = pos2t0[b*5 + t];
        t0s[t] = t0;
        int m = e1cnt[t0*4]; if (m > E1C) m = E1C;
        cm[t] = m;
        dvP[t] = rsqrtf(1.0f + (float)degCnt[posNode[b*5 + t]]);
    }
    __syncthreads();
    for (int i = t; i < 5*E1C; i += 256) {
        int p5 = i >> 7, j = i & (E1C-1);
        if (j < cm[p5]) slots[i] = markT[e1[(size_t)t0s[p5]*E1C + j]];
    }
    __syncthreads();
    for (int i = t; i < 5*HID; i += 256) {
        int p5 = i >> 7, f = i & 127;
        float acc = hsT[(size_t)t0s[p5]*HID + f];
        int m = cm[p5];
        const int* sp = &slots[p5*E1C];
        for (int j = 0; j < m; ++j) {
            int ts = sp[j];
            if (ts >= 0) acc += hsT[(size_t)ts*HID + f];
        }
        c[i] = fmaxf(acc*dvP[p5] + b2[f], 0.0f);
    }
    if (t < ALAST) c[5*HID + t] = actions[b*ALAST + t];
    if (t == ALAST) c[5*HID + ALAST] = steps[b];
    __syncthreads();
    int o = t >> 4, sub = t & 15;
    int j = jg*16 + o;
    const float* wr = Wp1 + (size_t)j*PROJ_IN;
    float s = 0.f;
    for (int k = sub; k < PROJ_IN; k += 16) s += c[k]*wr[k];
    #pragma unroll
    for (int d = 8; d; d >>= 1) s += __shfl_down(s, d, 16);
    if (sub == 0) hm[b*EMB + j] = fmaxf(s + bp1[j], 0.f);
}

// MLP2
__global__ __launch_bounds__(256) void k_mlp2(
        const float* __restrict__ hm, const float* __restrict__ Wp2,
        const float* __restrict__ bp2, float* __restrict__ out) {
    int b  = blockIdx.x >> 4;
    int jg = blockIdx.x & 15;
    int t  = threadIdx.x;
    __shared__ float c[EMB];
    if (t < EMB) c[t] = hm[b*EMB + t];
    __syncthreads();
    int o = t >> 4, sub = t & 15;
    int j = jg*16 + o;
    const float* wr = Wp2 + (size_t)j*EMB;
    float s = 0.f;
    for (int k = sub; k < EMB; k += 16) s += c[k]*wr[k];
    #pragma unroll
    for (int d = 8; d; d >>= 1) s += __shfl_down(s, d, 16);
    if (sub == 0) out[b*EMB + j] = s + bp2[j];
}

extern "C" void kernel_launch(void* const* d_in, const int* in_sizes, int n_in,
                              void* d_out, int out_size, void* d_ws, size_t ws_size,
                              hipStream_t stream) {
    const float* graph_x = (const float*)d_in[0];
    const int*   edges   = (const int*)d_in[1];
    const int*   pos     = (const int*)d_in[2];
    const int*   avail   = (const int*)d_in[3];
    const float* actions = (const float*)d_in[4];
    const float* steps   = (const float*)d_in[5];
    const float* W1  = (const float*)d_in[6];
    const float* b1  = (const float*)d_in[7];
    const float* W2  = (const float*)d_in[8];
    const float* b2  = (const float*)d_in[9];
    const float* Wp1 = (const float*)d_in[10];
    const float* bp1 = (const float*)d_in[11];
    const float* Wp2 = (const float*)d_in[12];
    const float* bp2 = (const float*)d_in[13];
    float* out = (float*)d_out;

    char* ws = (char*)d_ws;
    size_t off = 0;
    #define ALLOC(ptrname, type, nelem) \
        type* ptrname = (type*)(ws + off); off = (off + (size_t)(nelem)*sizeof(type) + 255) & ~(size_t)255;
    ALLOC(markT,   int,   NNODES)
    ALLOC(degCnt,  int,   NNODES)
    ALLOC(cnts,    int,   1024)
    ALLOC(e1cnt,   int,   TCAP*4)
    ALLOC(Tnodes,  int,   TCAP)
    ALLOC(pos2t0,  int,   NPOS)
    ALLOC(posNode, int,   NPOS)
    ALLOC(e0,      int,   NPOS*E0CAP)
    ALLOC(e1,      int,   (size_t)TCAP*E1C)
    ALLOC(axT,     float, (size_t)(TCAP+128)*FIN)
    ALLOC(hsT,     float, (size_t)TCAP*HID)
    ALLOC(hm,      float, (size_t)NB*EMB)
    #undef ALLOC

    k_clear<<<NBLK, 256, 0, stream>>>(markT, degCnt, cnts, e1cnt);
    k_mark<<<1, 64, 0, stream>>>(avail, pos, markT, Tnodes, cnts, pos2t0, posNode);
    k_pass1<<<NEDGE/4/256, 256, 0, stream>>>(edges, markT, cnts, e0);
    k_dedup<<<NPOS, 256, 0, stream>>>(e0, cnts, markT, Tnodes);
    k_pass2<<<NEDGE/4/256, 256, 0, stream>>>(edges, markT, e1cnt, e1, degCnt);
    k_pass3<<<NEDGE/4/256, 256, 0, stream>>>(edges, markT, degCnt);
    k_aggT<<<(TCAP+3)/4, 256, 0, stream>>>(e1cnt, e1, degCnt, cnts, graph_x, axT);
    k_h12T<<<2*((TCAP+127)/128), 256, 0, stream>>>(axT, Tnodes, degCnt, cnts,
                                                   graph_x, W1, b1, W2, hsT);
    k_mlp1<<<NB*16, 256, 0, stream>>>(pos2t0, posNode, e1cnt, e1, markT, hsT,
                                      degCnt, b2, actions, steps, Wp1, bp1, hm);
    k_mlp2<<<NB*16, 256, 0, stream>>>(hm, Wp2, bp2, out);
}